// Round 3
// baseline (351.097 us; speedup 1.0000x reference)
//
#include <hip/hip_runtime.h>

constexpr int B_ = 4, C_ = 5, H_ = 96, W_ = 96;
constexpr int N_ = H_ * W_;      // 9216
constexpr int NPT = N_ / 256;    // 36 elements per thread per row
constexpr int NJ = NPT / 4;      // 9 float4 per thread per row
constexpr int R_ = 4;            // rows per block (k-reuse factor)

typedef float f32x4 __attribute__((ext_vector_type(4)));

// ---------------- kernel 1: 1x1-conv projections q,k -> ws as [B][C][N] ----
__global__ __launch_bounds__(256) void proj_qk(
    const float* __restrict__ x,
    const float* __restrict__ wq, const float* __restrict__ bq,
    const float* __restrict__ wk, const float* __restrict__ bk,
    float* __restrict__ q, float* __restrict__ k)
{
    int idx = blockIdx.x * 256 + threadIdx.x;   // over B*N
    if (idx >= B_ * N_) return;
    int b = idx / N_;
    int n = idx - b * N_;
    float xi[C_];
#pragma unroll
    for (int i = 0; i < C_; ++i) xi[i] = x[(size_t)(b * C_ + i) * N_ + n];
#pragma unroll
    for (int c = 0; c < C_; ++c) {
        float aq = bq[c], ak = bk[c];
#pragma unroll
        for (int i = 0; i < C_; ++i) {
            aq = fmaf(wq[c * C_ + i], xi[i], aq);
            ak = fmaf(wk[c * C_ + i], xi[i], ak);
        }
        q[(size_t)(b * C_ + c) * N_ + n] = aq;
        k[(size_t)(b * C_ + c) * N_ + n] = ak;
    }
}

// ------- kernel 2: R_ rows per block; fused energy+softmax, k reused R_x ---
__global__ __launch_bounds__(256, 2) void attn_rows(
    const float* __restrict__ q, const float* __restrict__ k,
    float* __restrict__ out)
{
    constexpr int ROWS_PER_B = N_ / R_;          // 2304
    const int g  = blockIdx.x;                    // over B * ROWS_PER_B
    const int b  = g / ROWS_PER_B;
    const int n0 = (g - b * ROWS_PER_B) * R_;
    const int tid = threadIdx.x;

    // q vectors for the R_ rows (broadcast across the block)
    float qv[R_][C_];
#pragma unroll
    for (int r = 0; r < R_; ++r)
#pragma unroll
        for (int c = 0; c < C_; ++c)
            qv[r][c] = q[(size_t)(b * C_ + c) * N_ + (n0 + r)];

    const float* kb = k + (size_t)b * C_ * N_;

    // energy rows live entirely in registers: R_ x 9 float4 per thread
    f32x4 e[R_][NJ];
    float lmax[R_];
#pragma unroll
    for (int r = 0; r < R_; ++r) lmax[r] = -3.4e38f;

#pragma unroll
    for (int j = 0; j < NJ; ++j) {
        const int m4 = (j * 256 + tid) * 4;
        f32x4 kv[C_];
#pragma unroll
        for (int c = 0; c < C_; ++c)
            kv[c] = *reinterpret_cast<const f32x4*>(kb + (size_t)c * N_ + m4);
#pragma unroll
        for (int r = 0; r < R_; ++r) {
            f32x4 acc = {0.f, 0.f, 0.f, 0.f};
#pragma unroll
            for (int c = 0; c < C_; ++c) {
                acc.x = fmaf(qv[r][c], kv[c].x, acc.x);
                acc.y = fmaf(qv[r][c], kv[c].y, acc.y);
                acc.z = fmaf(qv[r][c], kv[c].z, acc.z);
                acc.w = fmaf(qv[r][c], kv[c].w, acc.w);
            }
            e[r][j] = acc;
            lmax[r] = fmaxf(lmax[r],
                            fmaxf(fmaxf(acc.x, acc.y), fmaxf(acc.z, acc.w)));
        }
    }

    __shared__ float redmax[R_][4];
    __shared__ float redsum[R_][4];
    const int wv = tid >> 6;

    // block max per row
#pragma unroll
    for (int r = 0; r < R_; ++r) {
        float m = lmax[r];
#pragma unroll
        for (int off = 32; off >= 1; off >>= 1)
            m = fmaxf(m, __shfl_xor(m, off, 64));
        if ((tid & 63) == 0) redmax[r][wv] = m;
    }
    __syncthreads();
    float rmax[R_];
#pragma unroll
    for (int r = 0; r < R_; ++r)
        rmax[r] = fmaxf(fmaxf(redmax[r][0], redmax[r][1]),
                        fmaxf(redmax[r][2], redmax[r][3]));

    // exp + block sum per row
#pragma unroll
    for (int r = 0; r < R_; ++r) {
        float s = 0.f;
#pragma unroll
        for (int j = 0; j < NJ; ++j) {
            e[r][j].x = __expf(e[r][j].x - rmax[r]);
            e[r][j].y = __expf(e[r][j].y - rmax[r]);
            e[r][j].z = __expf(e[r][j].z - rmax[r]);
            e[r][j].w = __expf(e[r][j].w - rmax[r]);
            s += (e[r][j].x + e[r][j].y) + (e[r][j].z + e[r][j].w);
        }
#pragma unroll
        for (int off = 32; off >= 1; off >>= 1)
            s += __shfl_xor(s, off, 64);
        if ((tid & 63) == 0) redsum[r][wv] = s;
    }
    __syncthreads();
    float inv[R_];
#pragma unroll
    for (int r = 0; r < R_; ++r)
        inv[r] = 1.f / ((redsum[r][0] + redsum[r][1]) +
                        (redsum[r][2] + redsum[r][3]));

    // scaled stores, float4-coalesced, nontemporal (never re-read)
#pragma unroll
    for (int r = 0; r < R_; ++r) {
        float* orow = out + (size_t)(b * N_ + n0 + r) * N_;
#pragma unroll
        for (int j = 0; j < NJ; ++j) {
            const int m4 = (j * 256 + tid) * 4;
            f32x4 o;
            o.x = e[r][j].x * inv[r];
            o.y = e[r][j].y * inv[r];
            o.z = e[r][j].z * inv[r];
            o.w = e[r][j].w * inv[r];
            __builtin_nontemporal_store(o, reinterpret_cast<f32x4*>(orow + m4));
        }
    }
}

extern "C" void kernel_launch(void* const* d_in, const int* in_sizes, int n_in,
                              void* d_out, int out_size, void* d_ws, size_t ws_size,
                              hipStream_t stream)
{
    const float* x  = (const float*)d_in[0];
    const float* wq = (const float*)d_in[1];
    const float* bq = (const float*)d_in[2];
    const float* wk = (const float*)d_in[3];
    const float* bk = (const float*)d_in[4];
    float* out = (float*)d_out;

    float* q = (float*)d_ws;                       // [B][C][N]
    float* k = q + (size_t)B_ * C_ * N_;           // [B][C][N]

    proj_qk<<<(B_ * N_ + 255) / 256, 256, 0, stream>>>(x, wq, bq, wk, bk, q, k);
    attn_rows<<<B_ * (N_ / R_), 256, 0, stream>>>(q, k, out);
}

// Round 4
// 330.945 us; speedup vs baseline: 1.0609x; 1.0609x over previous
//
#include <hip/hip_runtime.h>

constexpr int B_ = 4, C_ = 5, H_ = 96, W_ = 96;
constexpr int N_ = H_ * W_;      // 9216
constexpr int NPT = N_ / 256;    // 36 elements per thread per row
constexpr int NJ = NPT / 4;      // 9 float4 per thread per row
constexpr int R_ = 2;            // rows per block (k-reuse factor)

typedef float f32x4 __attribute__((ext_vector_type(4)));

// ---------------- kernel 1: 1x1-conv projections q,k -> ws as [B][C][N] ----
__global__ __launch_bounds__(256) void proj_qk(
    const float* __restrict__ x,
    const float* __restrict__ wq, const float* __restrict__ bq,
    const float* __restrict__ wk, const float* __restrict__ bk,
    float* __restrict__ q, float* __restrict__ k)
{
    int idx = blockIdx.x * 256 + threadIdx.x;   // over B*N
    if (idx >= B_ * N_) return;
    int b = idx / N_;
    int n = idx - b * N_;
    float xi[C_];
#pragma unroll
    for (int i = 0; i < C_; ++i) xi[i] = x[(size_t)(b * C_ + i) * N_ + n];
#pragma unroll
    for (int c = 0; c < C_; ++c) {
        float aq = bq[c], ak = bk[c];
#pragma unroll
        for (int i = 0; i < C_; ++i) {
            aq = fmaf(wq[c * C_ + i], xi[i], aq);
            ak = fmaf(wk[c * C_ + i], xi[i], ak);
        }
        q[(size_t)(b * C_ + c) * N_ + n] = aq;
        k[(size_t)(b * C_ + c) * N_ + n] = ak;
    }
}

// ------- kernel 2: R_ rows per block; fused energy+softmax, k reused R_x ---
__global__ __launch_bounds__(256) void attn_rows(
    const float* __restrict__ q, const float* __restrict__ k,
    float* __restrict__ out)
{
    constexpr int ROWS_PER_B = N_ / R_;
    const int g  = blockIdx.x;                    // over B * ROWS_PER_B
    const int b  = g / ROWS_PER_B;
    const int n0 = (g - b * ROWS_PER_B) * R_;
    const int tid = threadIdx.x;

    // q vectors for the R_ rows (broadcast across the block)
    float qv[R_][C_];
#pragma unroll
    for (int r = 0; r < R_; ++r)
#pragma unroll
        for (int c = 0; c < C_; ++c)
            qv[r][c] = q[(size_t)(b * C_ + c) * N_ + (n0 + r)];

    const float* kb = k + (size_t)b * C_ * N_;

    // energy rows live entirely in registers: R_ x 9 float4 per thread
    f32x4 e[R_][NJ];
    float lmax[R_];
#pragma unroll
    for (int r = 0; r < R_; ++r) lmax[r] = -3.4e38f;

#pragma unroll
    for (int j = 0; j < NJ; ++j) {
        const int m4 = (j * 256 + tid) * 4;
        f32x4 kv[C_];
#pragma unroll
        for (int c = 0; c < C_; ++c)
            kv[c] = *reinterpret_cast<const f32x4*>(kb + (size_t)c * N_ + m4);
#pragma unroll
        for (int r = 0; r < R_; ++r) {
            f32x4 acc = {0.f, 0.f, 0.f, 0.f};
#pragma unroll
            for (int c = 0; c < C_; ++c) {
                acc.x = fmaf(qv[r][c], kv[c].x, acc.x);
                acc.y = fmaf(qv[r][c], kv[c].y, acc.y);
                acc.z = fmaf(qv[r][c], kv[c].z, acc.z);
                acc.w = fmaf(qv[r][c], kv[c].w, acc.w);
            }
            e[r][j] = acc;
            lmax[r] = fmaxf(lmax[r],
                            fmaxf(fmaxf(acc.x, acc.y), fmaxf(acc.z, acc.w)));
        }
    }

    __shared__ float redmax[R_][4];
    __shared__ float redsum[R_][4];
    const int wv = tid >> 6;

    // block max per row
#pragma unroll
    for (int r = 0; r < R_; ++r) {
        float m = lmax[r];
#pragma unroll
        for (int off = 32; off >= 1; off >>= 1)
            m = fmaxf(m, __shfl_xor(m, off, 64));
        if ((tid & 63) == 0) redmax[r][wv] = m;
    }
    __syncthreads();
    float rmax[R_];
#pragma unroll
    for (int r = 0; r < R_; ++r)
        rmax[r] = fmaxf(fmaxf(redmax[r][0], redmax[r][1]),
                        fmaxf(redmax[r][2], redmax[r][3]));

    // exp + block sum per row
#pragma unroll
    for (int r = 0; r < R_; ++r) {
        float s = 0.f;
#pragma unroll
        for (int j = 0; j < NJ; ++j) {
            e[r][j].x = __expf(e[r][j].x - rmax[r]);
            e[r][j].y = __expf(e[r][j].y - rmax[r]);
            e[r][j].z = __expf(e[r][j].z - rmax[r]);
            e[r][j].w = __expf(e[r][j].w - rmax[r]);
            s += (e[r][j].x + e[r][j].y) + (e[r][j].z + e[r][j].w);
        }
#pragma unroll
        for (int off = 32; off >= 1; off >>= 1)
            s += __shfl_xor(s, off, 64);
        if ((tid & 63) == 0) redsum[r][wv] = s;
    }
    __syncthreads();
    float inv[R_];
#pragma unroll
    for (int r = 0; r < R_; ++r)
        inv[r] = 1.f / ((redsum[r][0] + redsum[r][1]) +
                        (redsum[r][2] + redsum[r][3]));

    // scaled stores, float4-coalesced
#pragma unroll
    for (int r = 0; r < R_; ++r) {
        float* orow = out + (size_t)(b * N_ + n0 + r) * N_;
#pragma unroll
        for (int j = 0; j < NJ; ++j) {
            const int m4 = (j * 256 + tid) * 4;
            f32x4 o;
            o.x = e[r][j].x * inv[r];
            o.y = e[r][j].y * inv[r];
            o.z = e[r][j].z * inv[r];
            o.w = e[r][j].w * inv[r];
            *reinterpret_cast<f32x4*>(orow + m4) = o;
        }
    }
}

extern "C" void kernel_launch(void* const* d_in, const int* in_sizes, int n_in,
                              void* d_out, int out_size, void* d_ws, size_t ws_size,
                              hipStream_t stream)
{
    const float* x  = (const float*)d_in[0];
    const float* wq = (const float*)d_in[1];
    const float* bq = (const float*)d_in[2];
    const float* wk = (const float*)d_in[3];
    const float* bk = (const float*)d_in[4];
    float* out = (float*)d_out;

    float* q = (float*)d_ws;                       // [B][C][N]
    float* k = q + (size_t)B_ * C_ * N_;           // [B][C][N]

    proj_qk<<<(B_ * N_ + 255) / 256, 256, 0, stream>>>(x, wq, bq, wk, bk, q, k);
    attn_rows<<<B_ * (N_ / R_), 256, 0, stream>>>(q, k, out);
}

// Round 5
// 282.007 us; speedup vs baseline: 1.2450x; 1.1735x over previous
//
#include <hip/hip_runtime.h>

constexpr int B_ = 4, C_ = 5, H_ = 96, W_ = 96;
constexpr int N_ = H_ * W_;      // 9216
constexpr int NPT = N_ / 256;    // 36 elements per thread
constexpr int NJ = NPT / 4;      // 9 float4 per thread

typedef float    f32x4 __attribute__((ext_vector_type(4)));
typedef _Float16 f16x4 __attribute__((ext_vector_type(4)));

// ---- kernel 1: 1x1-conv projections; q -> f32 [B][C][N], k -> f16 [B][C][N]
__global__ __launch_bounds__(256) void proj_qk(
    const float* __restrict__ x,
    const float* __restrict__ wq, const float* __restrict__ bq,
    const float* __restrict__ wk, const float* __restrict__ bk,
    float* __restrict__ q, _Float16* __restrict__ k)
{
    int idx = blockIdx.x * 256 + threadIdx.x;   // over B*N
    if (idx >= B_ * N_) return;
    int b = idx / N_;
    int n = idx - b * N_;
    float xi[C_];
#pragma unroll
    for (int i = 0; i < C_; ++i) xi[i] = x[(size_t)(b * C_ + i) * N_ + n];
#pragma unroll
    for (int c = 0; c < C_; ++c) {
        float aq = bq[c], ak = bk[c];
#pragma unroll
        for (int i = 0; i < C_; ++i) {
            aq = fmaf(wq[c * C_ + i], xi[i], aq);
            ak = fmaf(wk[c * C_ + i], xi[i], ak);
        }
        q[(size_t)(b * C_ + c) * N_ + n] = aq;
        k[(size_t)(b * C_ + c) * N_ + n] = (_Float16)ak;
    }
}

// ---- kernel 2: one block per output row; fused energy+softmax; fp16 k reads
__global__ __launch_bounds__(256) void attn_row(
    const float* __restrict__ q, const _Float16* __restrict__ k,
    float* __restrict__ out)
{
    const int row = blockIdx.x;          // b*N + n
    const int b = row / N_;
    const int n = row - b * N_;
    const int tid = threadIdx.x;

    // q vector for this row (5 scalars, broadcast across the block)
    float qv[C_];
#pragma unroll
    for (int c = 0; c < C_; ++c) qv[c] = q[(size_t)(b * C_ + c) * N_ + n];

    const _Float16* kb = k + (size_t)b * C_ * N_;

    // energy row lives entirely in registers: 9 x f32x4 per thread
    f32x4 e[NJ];
    float lmax = -3.4e38f;
#pragma unroll
    for (int j = 0; j < NJ; ++j) {
        const int m4 = (j * 256 + tid) * 4;
        f32x4 acc = {0.f, 0.f, 0.f, 0.f};
#pragma unroll
        for (int c = 0; c < C_; ++c) {
            const f16x4 kh = *reinterpret_cast<const f16x4*>(kb + (size_t)c * N_ + m4);
            acc.x = fmaf(qv[c], (float)kh.x, acc.x);
            acc.y = fmaf(qv[c], (float)kh.y, acc.y);
            acc.z = fmaf(qv[c], (float)kh.z, acc.z);
            acc.w = fmaf(qv[c], (float)kh.w, acc.w);
        }
        e[j] = acc;
        lmax = fmaxf(lmax, fmaxf(fmaxf(acc.x, acc.y), fmaxf(acc.z, acc.w)));
    }

    __shared__ float redmax[4];
    __shared__ float redsum[4];

    // block max (4 waves of 64)
#pragma unroll
    for (int off = 32; off >= 1; off >>= 1)
        lmax = fmaxf(lmax, __shfl_xor(lmax, off, 64));
    const int wv = tid >> 6;
    if ((tid & 63) == 0) redmax[wv] = lmax;
    __syncthreads();
    const float rmax = fmaxf(fmaxf(redmax[0], redmax[1]),
                             fmaxf(redmax[2], redmax[3]));

    // exp + block sum
    float lsum = 0.f;
#pragma unroll
    for (int j = 0; j < NJ; ++j) {
        e[j].x = __expf(e[j].x - rmax);
        e[j].y = __expf(e[j].y - rmax);
        e[j].z = __expf(e[j].z - rmax);
        e[j].w = __expf(e[j].w - rmax);
        lsum += (e[j].x + e[j].y) + (e[j].z + e[j].w);
    }
#pragma unroll
    for (int off = 32; off >= 1; off >>= 1)
        lsum += __shfl_xor(lsum, off, 64);
    if ((tid & 63) == 0) redsum[wv] = lsum;
    __syncthreads();
    const float inv = 1.f / ((redsum[0] + redsum[1]) + (redsum[2] + redsum[3]));

    // scaled store, float4-coalesced
    float* orow = out + (size_t)row * N_;
#pragma unroll
    for (int j = 0; j < NJ; ++j) {
        const int m4 = (j * 256 + tid) * 4;
        f32x4 o;
        o.x = e[j].x * inv;
        o.y = e[j].y * inv;
        o.z = e[j].z * inv;
        o.w = e[j].w * inv;
        *reinterpret_cast<f32x4*>(orow + m4) = o;
    }
}

extern "C" void kernel_launch(void* const* d_in, const int* in_sizes, int n_in,
                              void* d_out, int out_size, void* d_ws, size_t ws_size,
                              hipStream_t stream)
{
    const float* x  = (const float*)d_in[0];
    const float* wq = (const float*)d_in[1];
    const float* bq = (const float*)d_in[2];
    const float* wk = (const float*)d_in[3];
    const float* bk = (const float*)d_in[4];
    float* out = (float*)d_out;

    float*    q = (float*)d_ws;                        // [B][C][N] f32
    _Float16* k = (_Float16*)(q + (size_t)B_ * C_ * N_); // [B][C][N] f16

    proj_qk<<<(B_ * N_ + 255) / 256, 256, 0, stream>>>(x, wq, bq, wk, bk, q, k);
    attn_row<<<B_ * N_, 256, 0, stream>>>(q, k, out);
}